// Round 2
// baseline (154.471 us; speedup 1.0000x reference)
//
#include <hip/hip_runtime.h>
#include <hip/hip_bf16.h>

#define B 64
#define F 2048
#define BN 64
#define BK 32
#define KSPLIT 4
#define KCHUNK (F / KSPLIT)   // 512
#define NITER (KCHUNK / BK)   // 16
#define LDSW 40               // LDS row stride in shorts (80 B, 16B-aligned rows)
#define GS 4                  // g-slices per attn block

typedef __attribute__((ext_vector_type(8))) short bf16x8;
typedef __attribute__((ext_vector_type(4))) float f32x4;

#define PART_FLOATS (KSPLIT * 3 * B * F)  // 1,572,864 floats = 6 MB
#define KVC_FLOATS (B * 2 * F)            // 262,144 floats = 1 MB

// RTZ hi/lo split of two floats, packed into dwords of bf16 pairs via v_perm.
// hi = top 16 bits (trunc), lo = trunc(f - hi). Residual ~2^-16 rel; the
// dropped lo*lo MFMA term is also ~2^-16. 3 ops/float vs 10 for double-RTNE.
__device__ __forceinline__ void split2(float f0, float f1, int& hi, int& lo) {
  union { float f; unsigned u; } a, b;
  a.f = f0; b.f = f1;
  union { unsigned u; float f; } ha, hb;
  ha.u = a.u & 0xFFFF0000u;
  hb.u = b.u & 0xFFFF0000u;
  union { float f; unsigned u; } la, lb;
  la.f = f0 - ha.f;
  lb.f = f1 - hb.f;
  hi = (int)__builtin_amdgcn_perm(b.u, a.u, 0x07060302u);   // (hi16(f1)<<16)|hi16(f0)
  lo = (int)__builtin_amdgcn_perm(lb.u, la.u, 0x07060302u);
}

// C[b,f] = sum_k x[b,k] * W[f,k] via bf16 hi/lo split (3 MFMAs ~ fp32 accuracy).
// Split-K partials to part[(kb*3+mat)*B*F + ...].
__global__ __launch_bounds__(256) void qkv_gemm_kernel(
    const float* __restrict__ x, const float* __restrict__ Wq,
    const float* __restrict__ Wk, const float* __restrict__ Wv,
    float* __restrict__ part) {
  __shared__ __align__(16) short xs_hi[B][LDSW];
  __shared__ __align__(16) short xs_lo[B][LDSW];
  __shared__ __align__(16) short ws_hi[BN][LDSW];
  __shared__ __align__(16) short ws_lo[BN][LDSW];

  const int tid  = threadIdx.x;
  const int f0   = blockIdx.x * BN;
  const int kb   = blockIdx.y;
  const int mat  = blockIdx.z;
  const float* W = (mat == 0) ? Wq : (mat == 1) ? Wk : Wv;

  const int lrow = tid >> 2;           // 0..63 staging row
  const int lc0  = (tid & 3) << 3;     // 0,8,16,24 staging col (shorts)

  const int wave = tid >> 6;
  const int lane = tid & 63;
  const int l15  = lane & 15;
  const int quad = lane >> 4;

  const float* xg = x + lrow * F + kb * KCHUNK + lc0;
  const float* wg = W + (f0 + lrow) * F + kb * KCHUNK + lc0;

  f32x4 acc[4];
#pragma unroll
  for (int i = 0; i < 4; ++i) acc[i] = (f32x4){0.f, 0.f, 0.f, 0.f};

  float4 xa = *(const float4*)(xg);
  float4 xb = *(const float4*)(xg + 4);
  float4 wa = *(const float4*)(wg);
  float4 wb = *(const float4*)(wg + 4);

  for (int it = 0; it < NITER; ++it) {
    __syncthreads();  // previous iter's LDS reads done
    int4 xh, xl, wh, wl;
    split2(xa.x, xa.y, xh.x, xl.x);
    split2(xa.z, xa.w, xh.y, xl.y);
    split2(xb.x, xb.y, xh.z, xl.z);
    split2(xb.z, xb.w, xh.w, xl.w);
    split2(wa.x, wa.y, wh.x, wl.x);
    split2(wa.z, wa.w, wh.y, wl.y);
    split2(wb.x, wb.y, wh.z, wl.z);
    split2(wb.z, wb.w, wh.w, wl.w);
    *(int4*)&xs_hi[lrow][lc0] = xh;
    *(int4*)&xs_lo[lrow][lc0] = xl;
    *(int4*)&ws_hi[lrow][lc0] = wh;
    *(int4*)&ws_lo[lrow][lc0] = wl;
    __syncthreads();

    if (it + 1 < NITER) {  // prefetch next chunk under MFMA
      const float* xp = xg + (it + 1) * BK;
      const float* wp = wg + (it + 1) * BK;
      xa = *(const float4*)(xp);
      xb = *(const float4*)(xp + 4);
      wa = *(const float4*)(wp);
      wb = *(const float4*)(wp + 4);
    }

    bf16x8 a_hi = *(const bf16x8*)&xs_hi[(wave << 4) + l15][quad << 3];
    bf16x8 a_lo = *(const bf16x8*)&xs_lo[(wave << 4) + l15][quad << 3];
#pragma unroll
    for (int nt = 0; nt < 4; ++nt) {
      bf16x8 b_hi = *(const bf16x8*)&ws_hi[(nt << 4) + l15][quad << 3];
      bf16x8 b_lo = *(const bf16x8*)&ws_lo[(nt << 4) + l15][quad << 3];
      acc[nt] = __builtin_amdgcn_mfma_f32_16x16x32_bf16(a_hi, b_hi, acc[nt], 0, 0, 0);
      acc[nt] = __builtin_amdgcn_mfma_f32_16x16x32_bf16(a_hi, b_lo, acc[nt], 0, 0, 0);
      acc[nt] = __builtin_amdgcn_mfma_f32_16x16x32_bf16(a_lo, b_hi, acc[nt], 0, 0, 0);
    }
  }

  // epilogue: C/D layout col=lane&15, row=quad*4+reg (m89-verified)
  float* outp = part + (size_t)(kb * 3 + mat) * B * F;
#pragma unroll
  for (int nt = 0; nt < 4; ++nt) {
    int f = f0 + (nt << 4) + l15;
#pragma unroll
    for (int r = 0; r < 4; ++r) {
      int brow = (wave << 4) + (quad << 2) + r;
      outp[brow * F + f] = acc[nt][r];
    }
  }
}

// Per-b: sum k/v split-K partials, compact unmasked (k,v) pairs into kvc,
// record cnt, kmax/kmin over unmasked, and vsum over ALL g (all-masked fallback).
__global__ __launch_bounds__(256) void prep_kernel(
    const float* __restrict__ part, const int* __restrict__ mask,
    float* __restrict__ kvc, float* __restrict__ vsum,
    float* __restrict__ kmaxg, float* __restrict__ kming,
    int* __restrict__ cntg) {
  __shared__ int cnt;
  __shared__ float svs[4], smx[4], smn[4];

  const int b    = blockIdx.x;
  const int tid  = threadIdx.x;
  const int wave = tid >> 6;
  const int lane = tid & 63;

  if (tid == 0) cnt = 0;
  __syncthreads();

  float vs = 0.f, kmx = -3.4e38f, kmn = 3.4e38f;
  float* kvb = kvc + (size_t)b * 2 * F;

  for (int c = wave; c < F / 64; c += 4) {
    int g = (c << 6) + lane;
    float kg = 0.f, vg = 0.f;
#pragma unroll
    for (int p = 0; p < KSPLIT; ++p) {
      kg += part[((p * 3 + 1) * B + b) * F + g];
      vg += part[((p * 3 + 2) * B + b) * F + g];
    }
    vs += vg;
    bool act = (mask[b * F + g] != 0);
    unsigned long long bal = __ballot(act);
    int nw = __popcll(bal);
    int base = 0;
    if (lane == 0) base = atomicAdd(&cnt, nw);
    base = __shfl(base, 0);
    if (act) {
      int pos = base + __popcll(bal & ((1ull << lane) - 1ull));
      kvb[2 * pos]     = kg;
      kvb[2 * pos + 1] = vg;
      kmx = fmaxf(kmx, kg);
      kmn = fminf(kmn, kg);
    }
  }
#pragma unroll
  for (int o = 32; o > 0; o >>= 1) {
    vs += __shfl_xor(vs, o);
    kmx = fmaxf(kmx, __shfl_xor(kmx, o));
    kmn = fminf(kmn, __shfl_xor(kmn, o));
  }
  if (lane == 0) { svs[wave] = vs; smx[wave] = kmx; smn[wave] = kmn; }
  __syncthreads();
  if (tid == 0) {
    vsum[b]  = svs[0] + svs[1] + svs[2] + svs[3];
    kmaxg[b] = fmaxf(fmaxf(smx[0], smx[1]), fmaxf(smx[2], smx[3]));
    kming[b] = fminf(fminf(smn[0], smn[1]), fminf(smn[2], smn[3]));
    cntg[b]  = cnt;
  }
}

// attended[b,f] = sum_{g unmasked} exp(q_bf*k_g - m) v_g / sum exp(...),
// m = q_bf>=0 ? q_bf*kmax : q_bf*kmin (global per-b -> consistent across slices).
// Block = 1024 threads: 4 g-slices x 256 f; LDS reduce across slices.
__global__ __launch_bounds__(1024, 8) void attn_kernel(
    const float* __restrict__ part, const float* __restrict__ kvc,
    const float* __restrict__ vsum, const float* __restrict__ kmaxg,
    const float* __restrict__ kming, const int* __restrict__ cntg,
    float* __restrict__ out) {
  __shared__ float rn[GS][256];
  __shared__ float rd[GS][256];

  const int b     = blockIdx.x;
  const int tid   = threadIdx.x;
  const int fl    = tid & 255;
  const int slice = tid >> 8;
  const int fi    = blockIdx.y * 256 + fl;

  float s = 0.f;
#pragma unroll
  for (int p = 0; p < KSPLIT; ++p) s += part[((p * 3 + 0) * B + b) * F + fi];

  const int n = cntg[b];
  const int start = (slice * n) / GS;
  const int end   = ((slice + 1) * n) / GS;

  const float L2E = 1.44269504088896f;
  const float se  = s * L2E;
  const float nm2 = -se * ((s >= 0.f) ? kmaxg[b] : kming[b]);

  const float2* kv2 = (const float2*)(kvc + (size_t)b * 2 * F);

  float n0 = 0.f, n1 = 0.f, n2 = 0.f, n3 = 0.f;
  float d0 = 0.f, d1 = 0.f, d2 = 0.f, d3 = 0.f;
  int j = start;
  for (; j + 4 <= end; j += 4) {
    float2 p0 = kv2[j];
    float2 p1 = kv2[j + 1];
    float2 p2 = kv2[j + 2];
    float2 p3 = kv2[j + 3];
    float e0 = exp2f(fmaf(se, p0.x, nm2));
    float e1 = exp2f(fmaf(se, p1.x, nm2));
    float e2 = exp2f(fmaf(se, p2.x, nm2));
    float e3 = exp2f(fmaf(se, p3.x, nm2));
    n0 = fmaf(e0, p0.y, n0); d0 += e0;
    n1 = fmaf(e1, p1.y, n1); d1 += e1;
    n2 = fmaf(e2, p2.y, n2); d2 += e2;
    n3 = fmaf(e3, p3.y, n3); d3 += e3;
  }
  for (; j < end; ++j) {
    float2 p = kv2[j];
    float e = exp2f(fmaf(se, p.x, nm2));
    n0 = fmaf(e, p.y, n0); d0 += e;
  }
  rn[slice][fl] = (n0 + n1) + (n2 + n3);
  rd[slice][fl] = (d0 + d1) + (d2 + d3);
  __syncthreads();
  if (slice == 0) {
    float N = (rn[0][fl] + rn[1][fl]) + (rn[2][fl] + rn[3][fl]);
    float D = (rd[0][fl] + rd[1][fl]) + (rd[2][fl] + rd[3][fl]);
    out[b * F + fi] = (n > 0) ? (N / D) : (vsum[b] * (1.0f / (float)F));
  }
}

extern "C" void kernel_launch(void* const* d_in, const int* in_sizes, int n_in,
                              void* d_out, int out_size, void* d_ws, size_t ws_size,
                              hipStream_t stream) {
  const float* x  = (const float*)d_in[0];
  const int* mask = (const int*)d_in[1];
  const float* Wq = (const float*)d_in[2];
  const float* Wk = (const float*)d_in[3];
  const float* Wv = (const float*)d_in[4];
  float* out = (float*)d_out;

  float* part = (float*)d_ws;                 // 6 MB
  float* kvc  = part + PART_FLOATS;           // 1 MB
  float* vsum = kvc + KVC_FLOATS;             // B floats
  float* kmx  = vsum + B;
  float* kmn  = kmx + B;
  int*   cnt  = (int*)(kmn + B);

  dim3 gg(F / BN, KSPLIT, 3);
  qkv_gemm_kernel<<<gg, 256, 0, stream>>>(x, Wq, Wk, Wv, part);
  prep_kernel<<<B, 256, 0, stream>>>(part, mask, kvc, vsum, kmx, kmn, cnt);
  dim3 ga(B, F / 256);
  attn_kernel<<<ga, 1024, 0, stream>>>(part, kvc, vsum, kmx, kmn, cnt, out);
}

// Round 3
// 127.473 us; speedup vs baseline: 1.2118x; 1.2118x over previous
//
#include <hip/hip_runtime.h>
#include <hip/hip_bf16.h>

#define B 64
#define F 2048
#define BN 64
#define BK 32
#define KSPLIT 4
#define KCHUNK (F / KSPLIT)   // 512
#define NITER (KCHUNK / BK)   // 16
#define LDSW 40               // LDS row stride in shorts (80 B, 16B-aligned rows)
#define GS 4                  // g-slices per attn block
#define NSEG 4                // compaction segments per b

typedef __attribute__((ext_vector_type(8))) short bf16x8;
typedef __attribute__((ext_vector_type(4))) float f32x4;

#define PART_FLOATS (KSPLIT * 3 * B * F)  // 6 MB
#define KVC_FLOATS (B * 2 * F)            // 1 MB

#if __has_builtin(__builtin_amdgcn_exp2f)
#define EXP2(x) __builtin_amdgcn_exp2f(x)   // raw v_exp_f32, no denorm expansion
#else
#define EXP2(x) exp2f(x)
#endif

// RTZ hi/lo split of two floats, packed via v_perm. 3 ops/float.
__device__ __forceinline__ void split2(float f0, float f1, int& hi, int& lo) {
  union { float f; unsigned u; } a, b;
  a.f = f0; b.f = f1;
  union { unsigned u; float f; } ha, hb;
  ha.u = a.u & 0xFFFF0000u;
  hb.u = b.u & 0xFFFF0000u;
  union { float f; unsigned u; } la, lb;
  la.f = f0 - ha.f;
  lb.f = f1 - hb.f;
  hi = (int)__builtin_amdgcn_perm(b.u, a.u, 0x07060302u);
  lo = (int)__builtin_amdgcn_perm(lb.u, la.u, 0x07060302u);
}

// C[b,f] = sum_k x[b,k]*W[f,k], bf16 hi/lo split (3 MFMAs ~ fp32 accuracy).
// Split-K partials -> part[(kb*3+mat)*B*F]. LDS double-buffered, 1 barrier/iter.
__global__ __launch_bounds__(256) void qkv_gemm_kernel(
    const float* __restrict__ x, const float* __restrict__ Wq,
    const float* __restrict__ Wk, const float* __restrict__ Wv,
    float* __restrict__ part) {
  __shared__ __align__(16) short xs_hi[2][B][LDSW];
  __shared__ __align__(16) short xs_lo[2][B][LDSW];
  __shared__ __align__(16) short ws_hi[2][BN][LDSW];
  __shared__ __align__(16) short ws_lo[2][BN][LDSW];

  const int tid  = threadIdx.x;
  const int f0   = blockIdx.x * BN;
  const int kb   = blockIdx.y;
  const int mat  = blockIdx.z;
  const float* W = (mat == 0) ? Wq : (mat == 1) ? Wk : Wv;

  const int lrow = tid >> 2;           // staging row 0..63
  const int lc0  = (tid & 3) << 3;     // staging col (shorts) 0,8,16,24

  const int wave = tid >> 6;
  const int lane = tid & 63;
  const int l15  = lane & 15;
  const int quad = lane >> 4;

  const float* xg = x + lrow * F + kb * KCHUNK + lc0;
  const float* wg = W + (f0 + lrow) * F + kb * KCHUNK + lc0;

  f32x4 acc[4];
#pragma unroll
  for (int i = 0; i < 4; ++i) acc[i] = (f32x4){0.f, 0.f, 0.f, 0.f};

  float4 px[2][2], pw[2][2];
  px[0][0] = *(const float4*)(xg);
  px[0][1] = *(const float4*)(xg + 4);
  pw[0][0] = *(const float4*)(wg);
  pw[0][1] = *(const float4*)(wg + 4);

#pragma unroll
  for (int it = 0; it < NITER; ++it) {
    const int cur = it & 1, nxt = cur ^ 1;
    if (it + 1 < NITER) {  // prefetch next chunk into alternate regs
      const float* xp = xg + (it + 1) * BK;
      const float* wp = wg + (it + 1) * BK;
      px[nxt][0] = *(const float4*)(xp);
      px[nxt][1] = *(const float4*)(xp + 4);
      pw[nxt][0] = *(const float4*)(wp);
      pw[nxt][1] = *(const float4*)(wp + 4);
    }
    int4 xh, xl, wh, wl;
    split2(px[cur][0].x, px[cur][0].y, xh.x, xl.x);
    split2(px[cur][0].z, px[cur][0].w, xh.y, xl.y);
    split2(px[cur][1].x, px[cur][1].y, xh.z, xl.z);
    split2(px[cur][1].z, px[cur][1].w, xh.w, xl.w);
    split2(pw[cur][0].x, pw[cur][0].y, wh.x, wl.x);
    split2(pw[cur][0].z, pw[cur][0].w, wh.y, wl.y);
    split2(pw[cur][1].x, pw[cur][1].y, wh.z, wl.z);
    split2(pw[cur][1].z, pw[cur][1].w, wh.w, wl.w);
    *(int4*)&xs_hi[cur][lrow][lc0] = xh;
    *(int4*)&xs_lo[cur][lrow][lc0] = xl;
    *(int4*)&ws_hi[cur][lrow][lc0] = wh;
    *(int4*)&ws_lo[cur][lrow][lc0] = wl;
    __syncthreads();  // writes[cur] visible; prior iter's reads drained

    bf16x8 a_hi = *(const bf16x8*)&xs_hi[cur][(wave << 4) + l15][quad << 3];
    bf16x8 a_lo = *(const bf16x8*)&xs_lo[cur][(wave << 4) + l15][quad << 3];
#pragma unroll
    for (int nt = 0; nt < 4; ++nt) {
      bf16x8 b_hi = *(const bf16x8*)&ws_hi[cur][(nt << 4) + l15][quad << 3];
      bf16x8 b_lo = *(const bf16x8*)&ws_lo[cur][(nt << 4) + l15][quad << 3];
      acc[nt] = __builtin_amdgcn_mfma_f32_16x16x32_bf16(a_hi, b_hi, acc[nt], 0, 0, 0);
      acc[nt] = __builtin_amdgcn_mfma_f32_16x16x32_bf16(a_hi, b_lo, acc[nt], 0, 0, 0);
      acc[nt] = __builtin_amdgcn_mfma_f32_16x16x32_bf16(a_lo, b_hi, acc[nt], 0, 0, 0);
    }
  }

  // epilogue: C/D layout col=lane&15, row=quad*4+reg
  float* outp = part + (size_t)(kb * 3 + mat) * B * F;
#pragma unroll
  for (int nt = 0; nt < 4; ++nt) {
    int f = f0 + (nt << 4) + l15;
#pragma unroll
    for (int r = 0; r < 4; ++r) {
      int brow = (wave << 4) + (quad << 2) + r;
      outp[brow * F + f] = acc[nt][r];
    }
  }
}

// Per (b, seg of 512 g's): sum k/v split-K partials, compact unmasked pairs
// into segment region kvc[b*2F + seg*1024 ..], record per-seg cnt/kmax/kmin/vsum.
__global__ __launch_bounds__(256) void prep_kernel(
    const float* __restrict__ part, const int* __restrict__ mask,
    float* __restrict__ kvc, float* __restrict__ vsum4,
    float* __restrict__ kmax4, float* __restrict__ kmin4,
    int* __restrict__ cnt4) {
  __shared__ int cnt;
  __shared__ float svs[4], smx[4], smn[4];

  const int b    = blockIdx.x;
  const int seg  = blockIdx.y;
  const int tid  = threadIdx.x;
  const int wave = tid >> 6;
  const int lane = tid & 63;

  if (tid == 0) cnt = 0;
  __syncthreads();

  float vs = 0.f, kmx = -3.4e38f, kmn = 3.4e38f;
  float* kvb = kvc + (size_t)b * 2 * F + seg * 1024;  // 512-pair region

#pragma unroll
  for (int c = wave; c < 8; c += 4) {
    int g = seg * 512 + (c << 6) + lane;
    float kg = 0.f, vg = 0.f;
#pragma unroll
    for (int p = 0; p < KSPLIT; ++p) {
      kg += part[((p * 3 + 1) * B + b) * F + g];
      vg += part[((p * 3 + 2) * B + b) * F + g];
    }
    vs += vg;
    bool act = (mask[b * F + g] != 0);
    unsigned long long bal = __ballot(act);
    int nw = __popcll(bal);
    int base = 0;
    if (lane == 0) base = atomicAdd(&cnt, nw);
    base = __shfl(base, 0);
    if (act) {
      int pos = base + __popcll(bal & ((1ull << lane) - 1ull));
      kvb[2 * pos]     = kg;
      kvb[2 * pos + 1] = vg;
      kmx = fmaxf(kmx, kg);
      kmn = fminf(kmn, kg);
    }
  }
#pragma unroll
  for (int o = 32; o > 0; o >>= 1) {
    vs += __shfl_xor(vs, o);
    kmx = fmaxf(kmx, __shfl_xor(kmx, o));
    kmn = fminf(kmn, __shfl_xor(kmn, o));
  }
  if (lane == 0) { svs[wave] = vs; smx[wave] = kmx; smn[wave] = kmn; }
  __syncthreads();
  if (tid == 0) {
    vsum4[b * NSEG + seg] = svs[0] + svs[1] + svs[2] + svs[3];
    kmax4[b * NSEG + seg] = fmaxf(fmaxf(smx[0], smx[1]), fmaxf(smx[2], smx[3]));
    kmin4[b * NSEG + seg] = fminf(fminf(smn[0], smn[1]), fminf(smn[2], smn[3]));
    cnt4[b * NSEG + seg]  = cnt;
  }
}

// attended[b,f]: per wave, all 64 lanes share g (wave-uniform j) -> (k,v) come
// from LDS broadcast ds_read_b128. 3 VALU + 1 v_exp per element.
__global__ __launch_bounds__(1024, 8) void attn_kernel(
    const float* __restrict__ part, const float* __restrict__ kvc,
    const float* __restrict__ vsum4, const float* __restrict__ kmax4,
    const float* __restrict__ kming4, const int* __restrict__ cnt4,
    float* __restrict__ out) {
  __shared__ __align__(16) float kvs[4096];  // 16 KB: all segments for this b
  __shared__ float rn[GS][256];
  __shared__ float rd[GS][256];

  const int b     = blockIdx.x;
  const int tid   = threadIdx.x;
  const int fl    = tid & 255;
  const int slice = tid >> 8;          // wave-uniform
  const int fi    = blockIdx.y * 256 + fl;

  // stage compacted kv (16 KB, coalesced, one float4/thread)
  ((float4*)kvs)[tid] = ((const float4*)(kvc + (size_t)b * 2 * F))[tid];

  float s = 0.f;
#pragma unroll
  for (int p = 0; p < KSPLIT; ++p) s += part[((p * 3 + 0) * B + b) * F + fi];

  int cnts[NSEG];
  float km = -3.4e38f, kn = 3.4e38f;
  int ntot = 0;
  float vstot = 0.f;
#pragma unroll
  for (int g4 = 0; g4 < NSEG; ++g4) {
    cnts[g4] = cnt4[b * NSEG + g4];
    ntot += cnts[g4];
    km = fmaxf(km, kmax4[b * NSEG + g4]);
    kn = fminf(kn, kming4[b * NSEG + g4]);
    vstot += vsum4[b * NSEG + g4];
  }

  const float L2E = 1.44269504088896f;
  const float se  = s * L2E;
  const float nm2 = -se * ((s >= 0.f) ? km : kn);

  __syncthreads();  // staging visible

  float n0 = 0.f, n1 = 0.f, n2 = 0.f, n3 = 0.f;
  float d0 = 0.f, d1 = 0.f, d2 = 0.f, d3 = 0.f;
#pragma unroll
  for (int seg = 0; seg < NSEG; ++seg) {
    const int cnt   = cnts[seg];
    const int quads = cnt >> 1;                 // float4 groups (2 pairs)
    const int q0 = (slice * quads) / GS;
    const int q1 = ((slice + 1) * quads) / GS;
    const float* base = kvs + (seg << 10);
    int q = q0;
    for (; q + 2 <= q1; q += 2) {               // 2 x ds_read_b128 = 4 elements
      float4 p0 = *(const float4*)(base + 4 * q);
      float4 p1 = *(const float4*)(base + 4 * q + 4);
      float e0 = EXP2(fmaf(se, p0.x, nm2));
      float e1 = EXP2(fmaf(se, p0.z, nm2));
      float e2 = EXP2(fmaf(se, p1.x, nm2));
      float e3 = EXP2(fmaf(se, p1.z, nm2));
      n0 = fmaf(e0, p0.y, n0); d0 += e0;
      n1 = fmaf(e1, p0.w, n1); d1 += e1;
      n2 = fmaf(e2, p1.y, n2); d2 += e2;
      n3 = fmaf(e3, p1.w, n3); d3 += e3;
    }
    if (q < q1) {
      float4 p0 = *(const float4*)(base + 4 * q);
      float e0 = EXP2(fmaf(se, p0.x, nm2));
      float e1 = EXP2(fmaf(se, p0.z, nm2));
      n0 = fmaf(e0, p0.y, n0); d0 += e0;
      n1 = fmaf(e1, p0.w, n1); d1 += e1;
    }
    if ((slice == GS - 1) && (cnt & 1)) {       // odd tail pair
      float2 p = *(const float2*)(base + 2 * (cnt - 1));
      float e = EXP2(fmaf(se, p.x, nm2));
      n2 = fmaf(e, p.y, n2); d2 += e;
    }
  }
  rn[slice][fl] = (n0 + n1) + (n2 + n3);
  rd[slice][fl] = (d0 + d1) + (d2 + d3);
  __syncthreads();
  if (slice == 0) {
    float N = (rn[0][fl] + rn[1][fl]) + (rn[2][fl] + rn[3][fl]);
    float D = (rd[0][fl] + rd[1][fl]) + (rd[2][fl] + rd[3][fl]);
    out[b * F + fi] = (ntot > 0) ? (N / D) : (vstot * (1.0f / (float)F));
  }
}

extern "C" void kernel_launch(void* const* d_in, const int* in_sizes, int n_in,
                              void* d_out, int out_size, void* d_ws, size_t ws_size,
                              hipStream_t stream) {
  const float* x  = (const float*)d_in[0];
  const int* mask = (const int*)d_in[1];
  const float* Wq = (const float*)d_in[2];
  const float* Wk = (const float*)d_in[3];
  const float* Wv = (const float*)d_in[4];
  float* out = (float*)d_out;

  float* part  = (float*)d_ws;                 // 6 MB
  float* kvc   = part + PART_FLOATS;           // 1 MB
  float* vsum4 = kvc + KVC_FLOATS;             // B*NSEG floats
  float* kmx4  = vsum4 + B * NSEG;
  float* kmn4  = kmx4 + B * NSEG;
  int*   cnt4  = (int*)(kmn4 + B * NSEG);

  dim3 gg(F / BN, KSPLIT, 3);
  qkv_gemm_kernel<<<gg, 256, 0, stream>>>(x, Wq, Wk, Wv, part);
  dim3 gp(B, NSEG);
  prep_kernel<<<gp, 256, 0, stream>>>(part, mask, kvc, vsum4, kmx4, kmn4, cnt4);
  dim3 ga(B, F / 256);
  attn_kernel<<<ga, 1024, 0, stream>>>(part, kvc, vsum4, kmx4, kmn4, cnt4, out);
}

// Round 4
// 125.185 us; speedup vs baseline: 1.2339x; 1.0183x over previous
//
#include <hip/hip_runtime.h>
#include <hip/hip_bf16.h>

#define B 64
#define F 2048
#define BN 64
#define BK 32
#define KSPLIT 8
#define KCHUNK (F / KSPLIT)   // 256
#define NITER (KCHUNK / BK)   // 8
#define LDSW 40               // LDS row stride in shorts (80 B, 16B-aligned rows)
#define GS 4                  // g-slices per attn block
#define NSEG 4                // compaction segments per b

typedef __attribute__((ext_vector_type(8))) short bf16x8;
typedef __attribute__((ext_vector_type(4))) float f32x4;

#define PART_FLOATS (KSPLIT * 3 * B * F)  // 12.6 MB
#define KVC_FLOATS (B * 2 * F)            // 1 MB

#if __has_builtin(__builtin_amdgcn_exp2f)
#define EXP2(x) __builtin_amdgcn_exp2f(x)   // raw v_exp_f32, no denorm expansion
#else
#define EXP2(x) exp2f(x)
#endif

// RTZ hi/lo split of two floats, packed via v_perm. 3 ops/float.
__device__ __forceinline__ void split2(float f0, float f1, int& hi, int& lo) {
  union { float f; unsigned u; } a, b;
  a.f = f0; b.f = f1;
  union { unsigned u; float f; } ha, hb;
  ha.u = a.u & 0xFFFF0000u;
  hb.u = b.u & 0xFFFF0000u;
  union { float f; unsigned u; } la, lb;
  la.f = f0 - ha.f;
  lb.f = f1 - hb.f;
  hi = (int)__builtin_amdgcn_perm(b.u, a.u, 0x07060302u);
  lo = (int)__builtin_amdgcn_perm(lb.u, la.u, 0x07060302u);
}

// C[b,f] = sum_k x[b,k]*W[f,k], bf16 hi/lo split (3 MFMAs ~ fp32 accuracy).
// Split-K partials -> part[(kb*3+mat)*B*F]. LDS double-buffered, 1 barrier/iter.
// KSPLIT=8 -> 768 blocks = 3/CU for BW saturation against the 48 MB weight stream.
__global__ __launch_bounds__(256) void qkv_gemm_kernel(
    const float* __restrict__ x, const float* __restrict__ Wq,
    const float* __restrict__ Wk, const float* __restrict__ Wv,
    float* __restrict__ part) {
  __shared__ __align__(16) short xs_hi[2][B][LDSW];
  __shared__ __align__(16) short xs_lo[2][B][LDSW];
  __shared__ __align__(16) short ws_hi[2][BN][LDSW];
  __shared__ __align__(16) short ws_lo[2][BN][LDSW];

  const int tid  = threadIdx.x;
  const int f0   = blockIdx.x * BN;
  const int kb   = blockIdx.y;
  const int mat  = blockIdx.z;
  const float* W = (mat == 0) ? Wq : (mat == 1) ? Wk : Wv;

  const int lrow = tid >> 2;           // staging row 0..63
  const int lc0  = (tid & 3) << 3;     // staging col (shorts) 0,8,16,24

  const int wave = tid >> 6;
  const int lane = tid & 63;
  const int l15  = lane & 15;
  const int quad = lane >> 4;

  const float* xg = x + lrow * F + kb * KCHUNK + lc0;
  const float* wg = W + (f0 + lrow) * F + kb * KCHUNK + lc0;

  f32x4 acc[4];
#pragma unroll
  for (int i = 0; i < 4; ++i) acc[i] = (f32x4){0.f, 0.f, 0.f, 0.f};

  float4 px[2][2], pw[2][2];
  px[0][0] = *(const float4*)(xg);
  px[0][1] = *(const float4*)(xg + 4);
  pw[0][0] = *(const float4*)(wg);
  pw[0][1] = *(const float4*)(wg + 4);

#pragma unroll
  for (int it = 0; it < NITER; ++it) {
    const int cur = it & 1, nxt = cur ^ 1;
    if (it + 1 < NITER) {  // prefetch next chunk into alternate regs
      const float* xp = xg + (it + 1) * BK;
      const float* wp = wg + (it + 1) * BK;
      px[nxt][0] = *(const float4*)(xp);
      px[nxt][1] = *(const float4*)(xp + 4);
      pw[nxt][0] = *(const float4*)(wp);
      pw[nxt][1] = *(const float4*)(wp + 4);
    }
    int4 xh, xl, wh, wl;
    split2(px[cur][0].x, px[cur][0].y, xh.x, xl.x);
    split2(px[cur][0].z, px[cur][0].w, xh.y, xl.y);
    split2(px[cur][1].x, px[cur][1].y, xh.z, xl.z);
    split2(px[cur][1].z, px[cur][1].w, xh.w, xl.w);
    split2(pw[cur][0].x, pw[cur][0].y, wh.x, wl.x);
    split2(pw[cur][0].z, pw[cur][0].w, wh.y, wl.y);
    split2(pw[cur][1].x, pw[cur][1].y, wh.z, wl.z);
    split2(pw[cur][1].z, pw[cur][1].w, wh.w, wl.w);
    *(int4*)&xs_hi[cur][lrow][lc0] = xh;
    *(int4*)&xs_lo[cur][lrow][lc0] = xl;
    *(int4*)&ws_hi[cur][lrow][lc0] = wh;
    *(int4*)&ws_lo[cur][lrow][lc0] = wl;
    __syncthreads();  // writes[cur] visible; prior iter's reads drained

    bf16x8 a_hi = *(const bf16x8*)&xs_hi[cur][(wave << 4) + l15][quad << 3];
    bf16x8 a_lo = *(const bf16x8*)&xs_lo[cur][(wave << 4) + l15][quad << 3];
#pragma unroll
    for (int nt = 0; nt < 4; ++nt) {
      bf16x8 b_hi = *(const bf16x8*)&ws_hi[cur][(nt << 4) + l15][quad << 3];
      bf16x8 b_lo = *(const bf16x8*)&ws_lo[cur][(nt << 4) + l15][quad << 3];
      acc[nt] = __builtin_amdgcn_mfma_f32_16x16x32_bf16(a_hi, b_hi, acc[nt], 0, 0, 0);
      acc[nt] = __builtin_amdgcn_mfma_f32_16x16x32_bf16(a_hi, b_lo, acc[nt], 0, 0, 0);
      acc[nt] = __builtin_amdgcn_mfma_f32_16x16x32_bf16(a_lo, b_hi, acc[nt], 0, 0, 0);
    }
  }

  // epilogue: C/D layout col=lane&15, row=quad*4+reg
  float* outp = part + (size_t)(kb * 3 + mat) * B * F;
#pragma unroll
  for (int nt = 0; nt < 4; ++nt) {
    int f = f0 + (nt << 4) + l15;
#pragma unroll
    for (int r = 0; r < 4; ++r) {
      int brow = (wave << 4) + (quad << 2) + r;
      outp[brow * F + f] = acc[nt][r];
    }
  }
}

// Per (b, seg of 512 g's): sum k/v split-K partials, compact unmasked pairs
// into segment region kvc[b*2F + seg*1024 ..], record per-seg cnt/kmax/kmin/vsum.
__global__ __launch_bounds__(256) void prep_kernel(
    const float* __restrict__ part, const int* __restrict__ mask,
    float* __restrict__ kvc, float* __restrict__ vsum4,
    float* __restrict__ kmax4, float* __restrict__ kmin4,
    int* __restrict__ cnt4) {
  __shared__ int cnt;
  __shared__ float svs[4], smx[4], smn[4];

  const int b    = blockIdx.x;
  const int seg  = blockIdx.y;
  const int tid  = threadIdx.x;
  const int wave = tid >> 6;
  const int lane = tid & 63;

  if (tid == 0) cnt = 0;
  __syncthreads();

  float vs = 0.f, kmx = -3.4e38f, kmn = 3.4e38f;
  float* kvb = kvc + (size_t)b * 2 * F + seg * 1024;  // 512-pair region

#pragma unroll
  for (int c = wave; c < 8; c += 4) {
    int g = seg * 512 + (c << 6) + lane;
    float kg = 0.f, vg = 0.f;
#pragma unroll
    for (int p = 0; p < KSPLIT; ++p) {
      kg += part[((p * 3 + 1) * B + b) * F + g];
      vg += part[((p * 3 + 2) * B + b) * F + g];
    }
    vs += vg;
    bool act = (mask[b * F + g] != 0);
    unsigned long long bal = __ballot(act);
    int nw = __popcll(bal);
    int base = 0;
    if (lane == 0) base = atomicAdd(&cnt, nw);
    base = __shfl(base, 0);
    if (act) {
      int pos = base + __popcll(bal & ((1ull << lane) - 1ull));
      kvb[2 * pos]     = kg;
      kvb[2 * pos + 1] = vg;
      kmx = fmaxf(kmx, kg);
      kmn = fminf(kmn, kg);
    }
  }
#pragma unroll
  for (int o = 32; o > 0; o >>= 1) {
    vs += __shfl_xor(vs, o);
    kmx = fmaxf(kmx, __shfl_xor(kmx, o));
    kmn = fminf(kmn, __shfl_xor(kmn, o));
  }
  if (lane == 0) { svs[wave] = vs; smx[wave] = kmx; smn[wave] = kmn; }
  __syncthreads();
  if (tid == 0) {
    vsum4[b * NSEG + seg] = svs[0] + svs[1] + svs[2] + svs[3];
    kmax4[b * NSEG + seg] = fmaxf(fmaxf(smx[0], smx[1]), fmaxf(smx[2], smx[3]));
    kmin4[b * NSEG + seg] = fminf(fminf(smn[0], smn[1]), fminf(smn[2], smn[3]));
    cnt4[b * NSEG + seg]  = cnt;
  }
}

// attended[b,f]: per wave, all 64 lanes share g (wave-uniform j) -> (k,v) come
// from LDS broadcast ds_read_b128. 3 VALU + 1 v_exp per element, unrolled x8.
__global__ __launch_bounds__(1024, 8) void attn_kernel(
    const float* __restrict__ part, const float* __restrict__ kvc,
    const float* __restrict__ vsum4, const float* __restrict__ kmax4,
    const float* __restrict__ kming4, const int* __restrict__ cnt4,
    float* __restrict__ out) {
  __shared__ __align__(16) float kvs[4096];  // 16 KB: all segments for this b
  __shared__ float rn[GS][256];
  __shared__ float rd[GS][256];

  const int b     = blockIdx.x;
  const int tid   = threadIdx.x;
  const int fl    = tid & 255;
  const int slice = tid >> 8;          // wave-uniform
  const int fi    = blockIdx.y * 256 + fl;

  // stage compacted kv (16 KB, coalesced, one float4/thread)
  ((float4*)kvs)[tid] = ((const float4*)(kvc + (size_t)b * 2 * F))[tid];

  float s = 0.f;
#pragma unroll
  for (int p = 0; p < KSPLIT; ++p) s += part[((p * 3 + 0) * B + b) * F + fi];

  int cnts[NSEG];
  float km = -3.4e38f, kn = 3.4e38f;
  int ntot = 0;
  float vstot = 0.f;
#pragma unroll
  for (int g4 = 0; g4 < NSEG; ++g4) {
    cnts[g4] = cnt4[b * NSEG + g4];
    ntot += cnts[g4];
    km = fmaxf(km, kmax4[b * NSEG + g4]);
    kn = fminf(kn, kming4[b * NSEG + g4]);
    vstot += vsum4[b * NSEG + g4];
  }

  const float L2E = 1.44269504088896f;
  const float se  = s * L2E;
  const float nm2 = -se * ((s >= 0.f) ? km : kn);

  __syncthreads();  // staging visible

  float n0 = 0.f, n1 = 0.f, n2 = 0.f, n3 = 0.f;
  float d0 = 0.f, d1 = 0.f, d2 = 0.f, d3 = 0.f;
#pragma unroll
  for (int seg = 0; seg < NSEG; ++seg) {
    const int cnt   = cnts[seg];
    const int quads = cnt >> 1;                 // float4 groups (2 pairs)
    const int q0 = (slice * quads) / GS;
    const int q1 = ((slice + 1) * quads) / GS;
    const float* base = kvs + (seg << 10);
    int q = q0;
    for (; q + 4 <= q1; q += 4) {               // 4 x ds_read_b128 = 8 elements
      float4 p0 = *(const float4*)(base + 4 * q);
      float4 p1 = *(const float4*)(base + 4 * q + 4);
      float4 p2 = *(const float4*)(base + 4 * q + 8);
      float4 p3 = *(const float4*)(base + 4 * q + 12);
      float e0 = EXP2(fmaf(se, p0.x, nm2));
      float e1 = EXP2(fmaf(se, p0.z, nm2));
      float e2 = EXP2(fmaf(se, p1.x, nm2));
      float e3 = EXP2(fmaf(se, p1.z, nm2));
      float e4 = EXP2(fmaf(se, p2.x, nm2));
      float e5 = EXP2(fmaf(se, p2.z, nm2));
      float e6 = EXP2(fmaf(se, p3.x, nm2));
      float e7 = EXP2(fmaf(se, p3.z, nm2));
      n0 = fmaf(e0, p0.y, n0); d0 += e0;
      n1 = fmaf(e1, p0.w, n1); d1 += e1;
      n2 = fmaf(e2, p1.y, n2); d2 += e2;
      n3 = fmaf(e3, p1.w, n3); d3 += e3;
      n0 = fmaf(e4, p2.y, n0); d0 += e4;
      n1 = fmaf(e5, p2.w, n1); d1 += e5;
      n2 = fmaf(e6, p3.y, n2); d2 += e6;
      n3 = fmaf(e7, p3.w, n3); d3 += e7;
    }
    for (; q < q1; ++q) {
      float4 p0 = *(const float4*)(base + 4 * q);
      float e0 = EXP2(fmaf(se, p0.x, nm2));
      float e1 = EXP2(fmaf(se, p0.z, nm2));
      n0 = fmaf(e0, p0.y, n0); d0 += e0;
      n1 = fmaf(e1, p0.w, n1); d1 += e1;
    }
    if ((slice == GS - 1) && (cnt & 1)) {       // odd tail pair
      float2 p = *(const float2*)(base + 2 * (cnt - 1));
      float e = EXP2(fmaf(se, p.x, nm2));
      n2 = fmaf(e, p.y, n2); d2 += e;
    }
  }
  rn[slice][fl] = (n0 + n1) + (n2 + n3);
  rd[slice][fl] = (d0 + d1) + (d2 + d3);
  __syncthreads();
  if (slice == 0) {
    float N = (rn[0][fl] + rn[1][fl]) + (rn[2][fl] + rn[3][fl]);
    float D = (rd[0][fl] + rd[1][fl]) + (rd[2][fl] + rd[3][fl]);
    out[b * F + fi] = (ntot > 0) ? (N / D) : (vstot * (1.0f / (float)F));
  }
}

extern "C" void kernel_launch(void* const* d_in, const int* in_sizes, int n_in,
                              void* d_out, int out_size, void* d_ws, size_t ws_size,
                              hipStream_t stream) {
  const float* x  = (const float*)d_in[0];
  const int* mask = (const int*)d_in[1];
  const float* Wq = (const float*)d_in[2];
  const float* Wk = (const float*)d_in[3];
  const float* Wv = (const float*)d_in[4];
  float* out = (float*)d_out;

  float* part  = (float*)d_ws;                 // 12.6 MB
  float* kvc   = part + PART_FLOATS;           // 1 MB
  float* vsum4 = kvc + KVC_FLOATS;             // B*NSEG floats
  float* kmx4  = vsum4 + B * NSEG;
  float* kmn4  = kmx4 + B * NSEG;
  int*   cnt4  = (int*)(kmn4 + B * NSEG);

  dim3 gg(F / BN, KSPLIT, 3);
  qkv_gemm_kernel<<<gg, 256, 0, stream>>>(x, Wq, Wk, Wv, part);
  dim3 gp(B, NSEG);
  prep_kernel<<<gp, 256, 0, stream>>>(part, mask, kvc, vsum4, kmx4, kmn4, cnt4);
  dim3 ga(B, F / 256);
  attn_kernel<<<ga, 1024, 0, stream>>>(part, kvc, vsum4, kmx4, kmn4, cnt4, out);
}